// Round 7
// baseline (84.596 us; speedup 1.0000x reference)
//
#include <hip/hip_runtime.h>

// ---------------------------------------------------------------------------
// QnnFormerVQC: 4-qubit VQC, B=262144, fp32 in / fp32 out.
// Round-6 evidence: timed floor ~44us is harness ws-poison fill; our kernels
// ~32us (10x issue-bound estimate). Suspects: __sincosf scratch lowering,
// s_load/readlane coefficient delivery defeating pipelining.
// Round 7:
//   qnn_prep (1 block): shuffle-circuit U builder -> packed U (re/im
//     interleaved, row-major) in d_ws. Verified semantics (incl. the
//     reference _apmcx quirk: swap amps 7<->15).
//   qnn_main: stage packed U into LDS (128 coalesced float4), then per
//     element: v = kron of cos/sin (via __sinf/__cosf — no sincos-by-pointer),
//     psi = U v with 8 broadcast ds_read_b128 + 32 FMA per row (all
//     independent -> pipelineable), 12 observables, 3 float4 stores.
// ---------------------------------------------------------------------------

// --- shuffle-gate helpers (prep): lane holds one amplitude of one column ---

__device__ __forceinline__ void g_rx(float& ar, float& ai, int amp, int m,
                                     float c, float s, int cmask) {
    const float br = __shfl_xor(ar, 1 << m, 64);
    const float bi = __shfl_xor(ai, 1 << m, 64);
    const float nr = c * ar + s * bi;
    const float ni = c * ai - s * br;
    const bool act = (amp & cmask) == cmask;
    ar = act ? nr : ar;
    ai = act ? ni : ai;
}

__device__ __forceinline__ void g_ry(float& ar, float& ai, int amp, int m,
                                     float c, float s) {
    const float br = __shfl_xor(ar, 1 << m, 64);
    const float bi = __shfl_xor(ai, 1 << m, 64);
    const float sp = ((amp >> m) & 1) ? s : -s;
    ar = c * ar + sp * br;
    ai = c * ai + sp * bi;
}

__device__ __forceinline__ void g_rz(float& ar, float& ai, int amp, int m,
                                     float c, float s) {
    const float p = ((amp >> m) & 1) ? s : -s;
    const float nr = c * ar - p * ai;
    const float ni = c * ai + p * ar;
    ar = nr; ai = ni;
}

__device__ __forceinline__ void g_h(float& ar, float& ai, int amp, int m) {
    const float R = 0.70710678118654752440f;
    const float br = __shfl_xor(ar, 1 << m, 64);
    const float bi = __shfl_xor(ai, 1 << m, 64);
    const bool hi = (amp >> m) & 1;
    ar = hi ? R * (br - ar) : R * (ar + br);
    ai = hi ? R * (bi - ai) : R * (ai + bi);
}

__device__ __forceinline__ void g_swap(float& ar, float& ai, int m, bool act) {
    const float br = __shfl_xor(ar, 1 << m, 64);
    const float bi = __shfl_xor(ai, 1 << m, 64);
    ar = act ? br : ar;
    ai = act ? bi : ai;
}

// 1 block, 256 threads: thread = (col = tid>>4, amp = tid&15).
// Output layout (packed): Uout[amp*32 + 2*col] = Re U[amp][col], +1 = Im.
__global__ void qnn_prep(const float* __restrict__ W, const float* __restrict__ E,
                         const float* __restrict__ G, const float* __restrict__ Bt,
                         float* __restrict__ Uout) {
    __shared__ float2 cs[30];
    const int tid = threadIdx.x;

    if (tid < 30) {
        float th;
        if (tid < 12)      th = W[tid];
        else if (tid < 24) th = E[tid - 12];
        else if (tid < 27) th = G[tid - 24];
        else               th = Bt[tid - 27];
        const float h = 0.5f * th;
        cs[tid] = make_float2(__cosf(h), __sinf(h));
    }
    __syncthreads();

    const int col = tid >> 4;
    const int amp = tid & 15;
    float ar = (amp == col) ? 1.f : 0.f;
    float ai = 0.f;

    for (int l = 0; l < 3; ++l) {
#pragma unroll
        for (int q = 0; q < 4; ++q) {       // RX,RY,RZ with weights[l][q]
            const float2 cw = cs[l * 4 + q];
            g_rx(ar, ai, amp, 3 - q, cw.x, cw.y, 0);
            g_ry(ar, ai, amp, 3 - q, cw.x, cw.y);
            g_rz(ar, ai, amp, 3 - q, cw.x, cw.y);
        }
#pragma unroll
        for (int i = 0; i < 4; ++i) {       // CRX chain
            const float2 ce = cs[12 + l * 4 + i];
            g_rx(ar, ai, amp, 3 - ((i + 1) & 3), ce.x, ce.y, 1 << (3 - i));
        }
#pragma unroll
        for (int q = 0; q < 4; ++q) g_h(ar, ai, amp, 3 - q);     // H all
#pragma unroll
        for (int q = 0; q < 4; ++q) g_swap(ar, ai, 3 - q, true); // X all
        g_h(ar, ai, amp, 0);                                     // H(q3)
        g_swap(ar, ai, 3, (amp & 7) == 7);  // reference MCX: 7<->15
        g_h(ar, ai, amp, 0);                                     // H(q3)
#pragma unroll
        for (int q = 0; q < 4; ++q) g_swap(ar, ai, 3 - q, true); // X all
#pragma unroll
        for (int q = 0; q < 4; ++q) g_h(ar, ai, amp, 3 - q);     // H all
        {                                   // CX RZ(g) CX, i=0..2
            const float2 cg = cs[24 + l];
#pragma unroll
            for (int i = 0; i < 3; ++i) {
                const int cm = 1 << (3 - i);
                const int m  = 2 - i;
                g_swap(ar, ai, m, (amp & cm) == cm);
                g_rz(ar, ai, amp, m, cg.x, cg.y);
                g_swap(ar, ai, m, (amp & cm) == cm);
            }
        }
        {                                   // RX(beta) all
            const float2 cb = cs[27 + l];
#pragma unroll
            for (int q = 0; q < 4; ++q) g_rx(ar, ai, amp, 3 - q, cb.x, cb.y, 0);
        }
    }

    Uout[amp * 32 + 2 * col]     = ar;
    Uout[amp * 32 + 2 * col + 1] = ai;
}

__global__ __launch_bounds__(256, 4)
void qnn_main(const float* __restrict__ x, const float* __restrict__ Ug,
              float* __restrict__ out, int B) {
    __shared__ float Upk[512];   // row i: [Re0,Im0,Re1,Im1,...] at i*32

    const int tid = threadIdx.x;
    // Stage U into LDS: 128 coalesced float4 loads.
    if (tid < 128) {
        const float4 u4 = reinterpret_cast<const float4*>(Ug)[tid];
        *reinterpret_cast<float4*>(&Upk[tid * 4]) = u4;
    }

    const int b = blockIdx.x * 256 + tid;
    const float4 xv = reinterpret_cast<const float4*>(x)[b];

    const float h0 = 0.5f * xv.x, h1 = 0.5f * xv.y;
    const float h2 = 0.5f * xv.z, h3 = 0.5f * xv.w;
    const float c0 = __cosf(h0), s0 = __sinf(h0);
    const float c1 = __cosf(h1), s1 = __sinf(h1);
    const float c2 = __cosf(h2), s2 = __sinf(h2);
    const float c3 = __cosf(h3), s3 = __sinf(h3);

    const float t01[4] = { c0 * c1, c0 * s1, s0 * c1, s0 * s1 };
    const float t23[4] = { c2 * c3, c2 * s3, s2 * c3, s2 * s3 };
    float v[16];
#pragma unroll
    for (int i = 0; i < 16; ++i) v[i] = t01[i >> 2] * t23[i & 3];

    __syncthreads();

    // psi = U v : per row, 8 broadcast ds_read_b128 + 32 independent FMA.
    float pr[16], pi[16];
#pragma unroll
    for (int i = 0; i < 16; ++i) {
        float ar = 0.f, ai = 0.f;
#pragma unroll
        for (int k = 0; k < 8; ++k) {
            const float4 u4 = *reinterpret_cast<const float4*>(&Upk[i * 32 + k * 4]);
            ar = fmaf(u4.x, v[2 * k],     ar);
            ai = fmaf(u4.y, v[2 * k],     ai);
            ar = fmaf(u4.z, v[2 * k + 1], ar);
            ai = fmaf(u4.w, v[2 * k + 1], ai);
        }
        pr[i] = ar;
        pi[i] = ai;
    }

    float n[16];
#pragma unroll
    for (int i = 0; i < 16; ++i) n[i] = pr[i] * pr[i] + pi[i] * pi[i];

    float o[12];
#pragma unroll
    for (int q = 0; q < 4; ++q) {
        const int m = 3 - q;
        const int mask = 1 << m;
        float z = 0.f, cr = 0.f, ci = 0.f;
#pragma unroll
        for (int p = 0; p < 8; ++p) {
            const int i0 = ((p >> m) << (m + 1)) | (p & (mask - 1));
            const int i1 = i0 | mask;
            z  += n[i0] - n[i1];
            cr += pr[i0] * pr[i1] + pi[i0] * pi[i1];
            ci += pr[i0] * pi[i1] - pi[i0] * pr[i1];
        }
        o[q]     = z;
        o[4 + q] = 2.f * cr;
        o[8 + q] = 2.f * ci;
    }

    float4* op = reinterpret_cast<float4*>(out + (size_t)b * 12);
    op[0] = make_float4(o[0], o[1], o[2],  o[3]);
    op[1] = make_float4(o[4], o[5], o[6],  o[7]);
    op[2] = make_float4(o[8], o[9], o[10], o[11]);
}

extern "C" void kernel_launch(void* const* d_in, const int* in_sizes, int n_in,
                              void* d_out, int out_size, void* d_ws, size_t ws_size,
                              hipStream_t stream) {
    const float* x  = (const float*)d_in[0];
    const float* W  = (const float*)d_in[1];
    const float* E  = (const float*)d_in[2];
    const float* G  = (const float*)d_in[3];
    const float* Bt = (const float*)d_in[4];
    float* U   = (float*)d_ws;   // 512 floats, packed
    float* out = (float*)d_out;
    const int B = in_sizes[0] / 4;   // 262144

    hipLaunchKernelGGL(qnn_prep, dim3(1), dim3(256), 0, stream, W, E, G, Bt, U);
    hipLaunchKernelGGL(qnn_main, dim3(B / 256), dim3(256), 0, stream,
                       x, U, out, B);
}

// Round 8
// 79.399 us; speedup vs baseline: 1.0654x; 1.0654x over previous
//
#include <hip/hip_runtime.h>

// ---------------------------------------------------------------------------
// QnnFormerVQC: 4-qubit VQC, B=262144, fp32 in / fp32 out.
// Attribution model (r4-r7): harness poison floor ~45us (untouchable);
// best main = r4's plain-uniform-load matvec (~15us; compiler picks s_load —
// r6's readfirstlane pointer rebuild broke uniformity and cost +10us;
// r7's LDS broadcast cost +5us). Round 8:
//   qnn_prep: shuffle-circuit U builder with FUSED depth-57 chain
//     (RZ*RY*RX -> one 2x2 from LDS; diffusion = Z3*(XH)^3*S*(HX)^3*Z3 via
//     HXH=Z; CX*RZ(g)*CX chain = pure diagonal phase, 0 shuffles).
//   qnn_main: EXACT r4 structure (verified 15us-class).
// Circuit semantics = round-4..7 verified (incl. reference _apmcx quirk:
// swap amps 7<->15, NOT 14<->15).
// ---------------------------------------------------------------------------

struct Cx { float r, i; };
__device__ __forceinline__ Cx cmul(Cx a, Cx b) {
    return { a.r * b.r - a.i * b.i, a.r * b.i + a.i * b.r };
}
__device__ __forceinline__ Cx cadd(Cx a, Cx b) { return { a.r + b.r, a.i + b.i }; }

// Apply general complex 2x2 gate (wave-uniform M) to bit m; state lives one
// amp per lane across 16-lane groups. Optional control mask.
__device__ __forceinline__ void apply2(float& ar, float& ai, int amp, int m,
                                       float d0r, float d0i, float o0r, float o0i,
                                       float o1r, float o1i, float d1r, float d1i,
                                       int cmask) {
    const float br = __shfl_xor(ar, 1 << m, 64);
    const float bi = __shfl_xor(ai, 1 << m, 64);
    const bool hi = (amp >> m) & 1;
    const float dr = hi ? d1r : d0r, di = hi ? d1i : d0i;
    const float orr = hi ? o1r : o0r, oi = hi ? o1i : o0i;
    const float nr = dr * ar - di * ai + orr * br - oi * bi;
    const float ni = dr * ai + di * ar + orr * bi + oi * br;
    const bool act = (amp & cmask) == cmask;
    ar = act ? nr : ar;
    ai = act ? ni : ai;
}

// 1 block, 256 threads: thread = (col = tid>>4, amp = tid&15).
__global__ void qnn_prep(const float* __restrict__ W, const float* __restrict__ E,
                         const float* __restrict__ G, const float* __restrict__ Bt,
                         float* __restrict__ Uout) {   // Ur[256] then Ui[256]
    __shared__ float A[96];   // 12 fused RZ*RY*RX 2x2s, 8 floats each
    __shared__ float C[24];   // 12 CRX (c,s)
    __shared__ float Zz[12];  // per layer: cos(g/2),sin(g/2),cos(3g/2),sin(3g/2)
    __shared__ float Bx[6];   // per layer: RX(beta) (c,s)

    const int tid = threadIdx.x;

    // --- stage 0: parameter preprocessing by 30 threads ---
    if (tid < 12) {            // fused A = RZ*RY*RX(theta), theta = W[tid]
        const float h = 0.5f * W[tid];
        const float c = __cosf(h), s = __sinf(h);
        const Cx rx00 = {c, 0.f}, rx01 = {0.f, -s};
        const Cx ry00 = {c, 0.f}, ry01 = {-s, 0.f}, ry10 = {s, 0.f};
        // t = RY*RX  (rx10=rx01, rx11=rx00, ry11=ry00)
        const Cx t00 = cadd(cmul(ry00, rx00), cmul(ry01, rx01));
        const Cx t01 = cadd(cmul(ry00, rx01), cmul(ry01, rx00));
        const Cx t10 = cadd(cmul(ry10, rx00), cmul(ry00, rx01));
        const Cx t11 = cadd(cmul(ry10, rx01), cmul(ry00, rx00));
        // A = diag(e^{-ih}, e^{+ih}) * t
        const Cx e0 = {c, -s}, e1 = {c, s};
        const Cx a00 = cmul(e0, t00), a01 = cmul(e0, t01);
        const Cx a10 = cmul(e1, t10), a11 = cmul(e1, t11);
        float* o = &A[tid * 8];
        o[0] = a00.r; o[1] = a00.i; o[2] = a01.r; o[3] = a01.i;
        o[4] = a10.r; o[5] = a10.i; o[6] = a11.r; o[7] = a11.i;
    } else if (tid < 24) {     // CRX half-angle sincos
        const float h = 0.5f * E[tid - 12];
        C[(tid - 12) * 2]     = __cosf(h);
        C[(tid - 12) * 2 + 1] = __sinf(h);
    } else if (tid < 27) {     // ZZ diagonal: cos/sin of g/2 and 3g/2
        const float g = G[tid - 24];
        float* o = &Zz[(tid - 24) * 4];
        o[0] = __cosf(0.5f * g);  o[1] = __sinf(0.5f * g);
        o[2] = __cosf(1.5f * g);  o[3] = __sinf(1.5f * g);
    } else if (tid < 30) {     // RX(beta)
        const float h = 0.5f * Bt[tid - 27];
        Bx[(tid - 27) * 2]     = __cosf(h);
        Bx[(tid - 27) * 2 + 1] = __sinf(h);
    }
    __syncthreads();

    const int col = tid >> 4;
    const int amp = tid & 15;
    float ar = (amp == col) ? 1.f : 0.f;
    float ai = 0.f;

    // per-amp ZZ sign structure: msum = sum_i (q_i==q_{i+1} ? +1 : -1), i=0..2
    const int q0b = (amp >> 3) & 1, q1b = (amp >> 2) & 1;
    const int q2b = (amp >> 1) & 1, q3b = amp & 1;
    const int msum = ((q0b == q1b) ? 1 : -1) + ((q1b == q2b) ? 1 : -1)
                   + ((q2b == q3b) ? 1 : -1);
    const float R = 0.70710678118654752440f;

    for (int l = 0; l < 3; ++l) {
        // ---- fused RZ*RY*RX per qubit (depth 4) ----
#pragma unroll
        for (int q = 0; q < 4; ++q) {
            const float* M = &A[(l * 4 + q) * 8];
            apply2(ar, ai, amp, 3 - q, M[0], M[1], M[2], M[3],
                   M[4], M[5], M[6], M[7], 0);
        }
        // ---- CRX chain (depth 4) ----
#pragma unroll
        for (int i = 0; i < 4; ++i) {
            const float c = C[(l * 4 + i) * 2], s = C[(l * 4 + i) * 2 + 1];
            apply2(ar, ai, amp, 3 - ((i + 1) & 3),
                   c, 0.f, 0.f, -s, 0.f, -s, c, 0.f, 1 << (3 - i));
        }
        // ---- diffusion: Z3, XH on q0..q2, S(7<->15), HX on q0..q2, Z3 ----
        if (q3b) { ar = -ar; ai = -ai; }                    // Z on qubit 3
#pragma unroll
        for (int m = 3; m >= 1; --m)                        // XH = [[R,-R],[R,R]]
            apply2(ar, ai, amp, m, R, 0.f, -R, 0.f, R, 0.f, R, 0.f, 0);
        {   // S: swap amps 7 <-> 15 (partner across bit 3)
            const float br = __shfl_xor(ar, 8, 64);
            const float bi = __shfl_xor(ai, 8, 64);
            const bool act = (amp & 7) == 7;
            ar = act ? br : ar;
            ai = act ? bi : ai;
        }
#pragma unroll
        for (int m = 3; m >= 1; --m)                        // HX = [[R,R],[-R,R]]
            apply2(ar, ai, amp, m, R, 0.f, R, 0.f, -R, 0.f, R, 0.f, 0);
        if (q3b) { ar = -ar; ai = -ai; }                    // Z on qubit 3
        // ---- ZZ diagonal phase e^{-i*(g/2)*msum} (depth 0) ----
        {
            const float* z = &Zz[l * 4];
            const float cc = (msum == 3 || msum == -3) ? z[2] : z[0];
            const float s0 = (msum == 3 || msum == -3) ? z[3] : z[1];
            const float ss = (msum > 0) ? s0 : -s0;
            const float nr = ar * cc + ai * ss;
            const float ni = ai * cc - ar * ss;
            ar = nr; ai = ni;
        }
        // ---- RX(beta) on all (depth 4) ----
        {
            const float cb = Bx[l * 2], sb = Bx[l * 2 + 1];
#pragma unroll
            for (int q = 0; q < 4; ++q)
                apply2(ar, ai, amp, 3 - q, cb, 0.f, 0.f, -sb, 0.f, -sb, cb, 0.f, 0);
        }
    }

    // lane (col,amp) holds U[amp][col]
    Uout[amp * 16 + col]       = ar;
    Uout[256 + amp * 16 + col] = ai;
}

// EXACT r4 main (best measured class: plain uniform indexing -> s_load).
__global__ __launch_bounds__(256) void qnn_main(const float* __restrict__ x,
                                                const float* __restrict__ U,
                                                float* __restrict__ out, int B) {
    const int b = blockIdx.x * 256 + threadIdx.x;
    if (b >= B) return;

    const float4 xv = reinterpret_cast<const float4*>(x)[b];
    const float h0 = 0.5f * xv.x, h1 = 0.5f * xv.y;
    const float h2 = 0.5f * xv.z, h3 = 0.5f * xv.w;
    const float c0 = __cosf(h0), s0 = __sinf(h0);
    const float c1 = __cosf(h1), s1 = __sinf(h1);
    const float c2 = __cosf(h2), s2 = __sinf(h2);
    const float c3 = __cosf(h3), s3 = __sinf(h3);

    const float t01[4] = { c0 * c1, c0 * s1, s0 * c1, s0 * s1 };
    const float t23[4] = { c2 * c3, c2 * s3, s2 * c3, s2 * s3 };
    float v[16];
#pragma unroll
    for (int i = 0; i < 16; ++i) v[i] = t01[i >> 2] * t23[i & 3];

    float pr[16], pi[16];
#pragma unroll
    for (int i = 0; i < 16; ++i) {
        float ar = 0.f, ai = 0.f;
#pragma unroll
        for (int j = 0; j < 16; ++j) {
            ar = fmaf(U[i * 16 + j], v[j], ar);
            ai = fmaf(U[256 + i * 16 + j], v[j], ai);
        }
        pr[i] = ar;
        pi[i] = ai;
    }

    float n[16];
#pragma unroll
    for (int i = 0; i < 16; ++i) n[i] = pr[i] * pr[i] + pi[i] * pi[i];

    float o[12];
#pragma unroll
    for (int q = 0; q < 4; ++q) {
        const int m = 3 - q;
        const int mask = 1 << m;
        float z = 0.f, cr = 0.f, ci = 0.f;
#pragma unroll
        for (int p = 0; p < 8; ++p) {
            const int i0 = ((p >> m) << (m + 1)) | (p & (mask - 1));
            const int i1 = i0 | mask;
            z  += n[i0] - n[i1];
            cr += pr[i0] * pr[i1] + pi[i0] * pi[i1];
            ci += pr[i0] * pi[i1] - pi[i0] * pr[i1];
        }
        o[q]     = z;
        o[4 + q] = 2.f * cr;
        o[8 + q] = 2.f * ci;
    }

    float4* op = reinterpret_cast<float4*>(out + (size_t)b * 12);
    op[0] = make_float4(o[0], o[1], o[2],  o[3]);
    op[1] = make_float4(o[4], o[5], o[6],  o[7]);
    op[2] = make_float4(o[8], o[9], o[10], o[11]);
}

extern "C" void kernel_launch(void* const* d_in, const int* in_sizes, int n_in,
                              void* d_out, int out_size, void* d_ws, size_t ws_size,
                              hipStream_t stream) {
    const float* x  = (const float*)d_in[0];
    const float* W  = (const float*)d_in[1];
    const float* E  = (const float*)d_in[2];
    const float* G  = (const float*)d_in[3];
    const float* Bt = (const float*)d_in[4];
    float* U   = (float*)d_ws;   // 512 floats
    float* out = (float*)d_out;
    const int B = in_sizes[0] / 4;   // 262144

    hipLaunchKernelGGL(qnn_prep, dim3(1), dim3(256), 0, stream, W, E, G, Bt, U);
    hipLaunchKernelGGL(qnn_main, dim3((B + 255) / 256), dim3(256), 0, stream,
                       x, U, out, B);
}

// Round 9
// 78.147 us; speedup vs baseline: 1.0825x; 1.0160x over previous
//
#include <hip/hip_runtime.h>

// ---------------------------------------------------------------------------
// QnnFormerVQC: 4-qubit VQC, B=262144, fp32 in / fp32 out.
// Round-8 finding: the harness's 268MB d_ws poison fill between timed
// iterations flushes L2 -> every kernel runs with COLD icache from HBM.
// Code bytes ~= time: r4 50KB prep = 67us; ~3KB prep = 19.8us; ~3KB main
// = 14.6us (exec roofline only ~2.8us). Round 9:
//   qnn_prep: 256 redundant blocks (parallel icache warming across CUs/XCDs),
//     only block 0 stores U. Fused depth-57 shuffle chain (r8, verified).
//   qnn_main: r4 structure; U in packed [Re,Im]-interleaved rows (32 floats,
//     one s_load_dwordx16 pair per row; re/im in adjacent SGPR pairs to
//     invite v_pk_fma_f32). Worst case op-identical to r4.
// Circuit semantics = rounds 4..8 verified (incl. reference _apmcx quirk:
// swap amps 7<->15, NOT 14<->15).
// ---------------------------------------------------------------------------

struct Cx { float r, i; };
__device__ __forceinline__ Cx cmul(Cx a, Cx b) {
    return { a.r * b.r - a.i * b.i, a.r * b.i + a.i * b.r };
}
__device__ __forceinline__ Cx cadd(Cx a, Cx b) { return { a.r + b.r, a.i + b.i }; }

// Apply general complex 2x2 gate (wave-uniform M) to bit m; state lives one
// amp per lane across 16-lane groups. Optional control mask.
__device__ __forceinline__ void apply2(float& ar, float& ai, int amp, int m,
                                       float d0r, float d0i, float o0r, float o0i,
                                       float o1r, float o1i, float d1r, float d1i,
                                       int cmask) {
    const float br = __shfl_xor(ar, 1 << m, 64);
    const float bi = __shfl_xor(ai, 1 << m, 64);
    const bool hi = (amp >> m) & 1;
    const float dr = hi ? d1r : d0r, di = hi ? d1i : d0i;
    const float orr = hi ? o1r : o0r, oi = hi ? o1i : o0i;
    const float nr = dr * ar - di * ai + orr * br - oi * bi;
    const float ni = dr * ai + di * ar + orr * bi + oi * br;
    const bool act = (amp & cmask) == cmask;
    ar = act ? nr : ar;
    ai = act ? ni : ai;
}

// 256 blocks execute redundantly (parallel icache warm); block 0 stores.
// Packed output: Uout[amp*32 + 2*col] = Re U[amp][col], +1 = Im.
__global__ void qnn_prep(const float* __restrict__ W, const float* __restrict__ E,
                         const float* __restrict__ G, const float* __restrict__ Bt,
                         float* __restrict__ Uout) {
    __shared__ float A[96];   // 12 fused RZ*RY*RX 2x2s, 8 floats each
    __shared__ float C[24];   // 12 CRX (c,s)
    __shared__ float Zz[12];  // per layer: cos(g/2),sin(g/2),cos(3g/2),sin(3g/2)
    __shared__ float Bx[6];   // per layer: RX(beta) (c,s)

    const int tid = threadIdx.x;

    if (tid < 12) {            // fused A = RZ*RY*RX(theta), theta = W[tid]
        const float h = 0.5f * W[tid];
        const float c = __cosf(h), s = __sinf(h);
        const Cx rx00 = {c, 0.f}, rx01 = {0.f, -s};
        const Cx ry00 = {c, 0.f}, ry01 = {-s, 0.f}, ry10 = {s, 0.f};
        const Cx t00 = cadd(cmul(ry00, rx00), cmul(ry01, rx01));
        const Cx t01 = cadd(cmul(ry00, rx01), cmul(ry01, rx00));
        const Cx t10 = cadd(cmul(ry10, rx00), cmul(ry00, rx01));
        const Cx t11 = cadd(cmul(ry10, rx01), cmul(ry00, rx00));
        const Cx e0 = {c, -s}, e1 = {c, s};
        const Cx a00 = cmul(e0, t00), a01 = cmul(e0, t01);
        const Cx a10 = cmul(e1, t10), a11 = cmul(e1, t11);
        float* o = &A[tid * 8];
        o[0] = a00.r; o[1] = a00.i; o[2] = a01.r; o[3] = a01.i;
        o[4] = a10.r; o[5] = a10.i; o[6] = a11.r; o[7] = a11.i;
    } else if (tid < 24) {     // CRX half-angle sincos
        const float h = 0.5f * E[tid - 12];
        C[(tid - 12) * 2]     = __cosf(h);
        C[(tid - 12) * 2 + 1] = __sinf(h);
    } else if (tid < 27) {     // ZZ diagonal: cos/sin of g/2 and 3g/2
        const float g = G[tid - 24];
        float* o = &Zz[(tid - 24) * 4];
        o[0] = __cosf(0.5f * g);  o[1] = __sinf(0.5f * g);
        o[2] = __cosf(1.5f * g);  o[3] = __sinf(1.5f * g);
    } else if (tid < 30) {     // RX(beta)
        const float h = 0.5f * Bt[tid - 27];
        Bx[(tid - 27) * 2]     = __cosf(h);
        Bx[(tid - 27) * 2 + 1] = __sinf(h);
    }
    __syncthreads();

    const int col = tid >> 4;
    const int amp = tid & 15;
    float ar = (amp == col) ? 1.f : 0.f;
    float ai = 0.f;

    const int q0b = (amp >> 3) & 1, q1b = (amp >> 2) & 1;
    const int q2b = (amp >> 1) & 1, q3b = amp & 1;
    const int msum = ((q0b == q1b) ? 1 : -1) + ((q1b == q2b) ? 1 : -1)
                   + ((q2b == q3b) ? 1 : -1);
    const float R = 0.70710678118654752440f;

    for (int l = 0; l < 3; ++l) {
#pragma unroll
        for (int q = 0; q < 4; ++q) {       // fused RZ*RY*RX per qubit
            const float* M = &A[(l * 4 + q) * 8];
            apply2(ar, ai, amp, 3 - q, M[0], M[1], M[2], M[3],
                   M[4], M[5], M[6], M[7], 0);
        }
#pragma unroll
        for (int i = 0; i < 4; ++i) {       // CRX chain
            const float c = C[(l * 4 + i) * 2], s = C[(l * 4 + i) * 2 + 1];
            apply2(ar, ai, amp, 3 - ((i + 1) & 3),
                   c, 0.f, 0.f, -s, 0.f, -s, c, 0.f, 1 << (3 - i));
        }
        // diffusion: Z3, XH on q0..q2, S(7<->15), HX on q0..q2, Z3
        if (q3b) { ar = -ar; ai = -ai; }
#pragma unroll
        for (int m = 3; m >= 1; --m)
            apply2(ar, ai, amp, m, R, 0.f, -R, 0.f, R, 0.f, R, 0.f, 0);
        {
            const float br = __shfl_xor(ar, 8, 64);
            const float bi = __shfl_xor(ai, 8, 64);
            const bool act = (amp & 7) == 7;
            ar = act ? br : ar;
            ai = act ? bi : ai;
        }
#pragma unroll
        for (int m = 3; m >= 1; --m)
            apply2(ar, ai, amp, m, R, 0.f, R, 0.f, -R, 0.f, R, 0.f, 0);
        if (q3b) { ar = -ar; ai = -ai; }
        // ZZ diagonal phase e^{-i*(g/2)*msum}
        {
            const float* z = &Zz[l * 4];
            const float cc = (msum == 3 || msum == -3) ? z[2] : z[0];
            const float s0 = (msum == 3 || msum == -3) ? z[3] : z[1];
            const float ss = (msum > 0) ? s0 : -s0;
            const float nr = ar * cc + ai * ss;
            const float ni = ai * cc - ar * ss;
            ar = nr; ai = ni;
        }
        // RX(beta) on all
        {
            const float cb = Bx[l * 2], sb = Bx[l * 2 + 1];
#pragma unroll
            for (int q = 0; q < 4; ++q)
                apply2(ar, ai, amp, 3 - q, cb, 0.f, 0.f, -sb, 0.f, -sb, cb, 0.f, 0);
        }
    }

    if (blockIdx.x == 0) {
        Uout[amp * 32 + 2 * col]     = ar;
        Uout[amp * 32 + 2 * col + 1] = ai;
    }
}

// r4-class main; U rows packed [Re,Im] interleaved (32 floats contiguous).
__global__ __launch_bounds__(256) void qnn_main(const float* __restrict__ x,
                                                const float* __restrict__ U,
                                                float* __restrict__ out) {
    const int b = blockIdx.x * 256 + threadIdx.x;

    const float4 xv = reinterpret_cast<const float4*>(x)[b];
    const float h0 = 0.5f * xv.x, h1 = 0.5f * xv.y;
    const float h2 = 0.5f * xv.z, h3 = 0.5f * xv.w;
    const float c0 = __cosf(h0), s0 = __sinf(h0);
    const float c1 = __cosf(h1), s1 = __sinf(h1);
    const float c2 = __cosf(h2), s2 = __sinf(h2);
    const float c3 = __cosf(h3), s3 = __sinf(h3);

    const float t01[4] = { c0 * c1, c0 * s1, s0 * c1, s0 * s1 };
    const float t23[4] = { c2 * c3, c2 * s3, s2 * c3, s2 * s3 };
    float v[16];
#pragma unroll
    for (int i = 0; i < 16; ++i) v[i] = t01[i >> 2] * t23[i & 3];

    float pr[16], pi[16];
#pragma unroll
    for (int i = 0; i < 16; ++i) {
        float ar = 0.f, ai = 0.f;
#pragma unroll
        for (int j = 0; j < 16; ++j) {
            ar = fmaf(U[i * 32 + 2 * j],     v[j], ar);
            ai = fmaf(U[i * 32 + 2 * j + 1], v[j], ai);
        }
        pr[i] = ar;
        pi[i] = ai;
    }

    float n[16];
#pragma unroll
    for (int i = 0; i < 16; ++i) n[i] = pr[i] * pr[i] + pi[i] * pi[i];

    float o[12];
#pragma unroll
    for (int q = 0; q < 4; ++q) {
        const int m = 3 - q;
        const int mask = 1 << m;
        float z = 0.f, cr = 0.f, ci = 0.f;
#pragma unroll
        for (int p = 0; p < 8; ++p) {
            const int i0 = ((p >> m) << (m + 1)) | (p & (mask - 1));
            const int i1 = i0 | mask;
            z  += n[i0] - n[i1];
            cr += pr[i0] * pr[i1] + pi[i0] * pi[i1];
            ci += pr[i0] * pi[i1] - pi[i0] * pr[i1];
        }
        o[q]     = z;
        o[4 + q] = 2.f * cr;
        o[8 + q] = 2.f * ci;
    }

    float4* op = reinterpret_cast<float4*>(out + (size_t)b * 12);
    op[0] = make_float4(o[0], o[1], o[2],  o[3]);
    op[1] = make_float4(o[4], o[5], o[6],  o[7]);
    op[2] = make_float4(o[8], o[9], o[10], o[11]);
}

extern "C" void kernel_launch(void* const* d_in, const int* in_sizes, int n_in,
                              void* d_out, int out_size, void* d_ws, size_t ws_size,
                              hipStream_t stream) {
    const float* x  = (const float*)d_in[0];
    const float* W  = (const float*)d_in[1];
    const float* E  = (const float*)d_in[2];
    const float* G  = (const float*)d_in[3];
    const float* Bt = (const float*)d_in[4];
    float* U   = (float*)d_ws;   // 512 floats, packed re/im
    float* out = (float*)d_out;
    const int B = in_sizes[0] / 4;   // 262144

    hipLaunchKernelGGL(qnn_prep, dim3(256), dim3(256), 0, stream, W, E, G, Bt, U);
    hipLaunchKernelGGL(qnn_main, dim3(B / 256), dim3(256), 0, stream, x, U, out);
}